// Round 5
// baseline (2528.724 us; speedup 1.0000x reference)
//
#include <hip/hip_runtime.h>
#include <cstdint>
#include <cmath>

#define L_ 12
#define H_ 768
#define NH_ 12
#define DN_ 32
#define DR_ 32
#define DV_ 64
#define R_ 512
#define E_ 8
#define I_ 256
#define SI_ 1024
#define B_ 2
#define S_ 512
#define T_ (B_*S_)
#define MOECAP 2560   // 2048 rows + up to 8*63 pad, rounded
#define NQKV 1312     // 768 (wq) + 544 (wkva) fused

typedef _Float16 half_t;
typedef __attribute__((ext_vector_type(8))) _Float16 half8;
typedef __attribute__((ext_vector_type(4))) float floatx4;

union HPk { half8 v; half_t u[8]; };

__device__ inline half_t f2h(float f){ return (half_t)f; }
__device__ inline float h2f(half_t h){ return (float)h; }

__device__ inline float blockReduceSum256(float v){
  __shared__ float red[4];
  float w = v;
  #pragma unroll
  for (int o = 32; o > 0; o >>= 1) w += __shfl_down(w, o, 64);
  __syncthreads();
  if ((threadIdx.x & 63) == 0) red[threadIdx.x >> 6] = w;
  __syncthreads();
  return red[0] + red[1] + red[2] + red[3];
}

// ---------------- GEMM: C[M,N] = A[M,K] * W[N,K]^T, fp16 in, fp32 acc ----
// 2-phase double-buffered pipeline, one barrier per K-step.
// TM = 128 (dense) or 64 (MoE, expert segments are 64-aligned). TN = 64.
enum { GM_F32OUT=0, GM_H16OUT=1, GM_QKV=2, GM_RESADD=4, GM_SILU=5, GM_MOE13=6, GM_MOE2=7 };

template<int MODE, int TM>
__global__ __launch_bounds__(256)
void gemm_k(const half_t* __restrict__ Ab, int lda,
            const half_t* __restrict__ Wb, int ldw,
            const half_t* __restrict__ W3b,
            void* __restrict__ Cg, int ldc,
            int M, int N, int Kd,
            const float* __restrict__ bias,
            float* __restrict__ hres,
            const int* __restrict__ tok,
            const float* __restrict__ rw,
            const int* __restrict__ poff,
            const float* __restrict__ cosb,
            const float* __restrict__ sinb,
            half_t* __restrict__ kpe,
            float* __restrict__ ckv)
{
  constexpr bool FUSED = (MODE==GM_SILU || MODE==GM_MOE13);
  constexpr bool MOE   = (MODE==GM_MOE13 || MODE==GM_MOE2);
  constexpr int  MFR   = TM/32;   // M-frags per wave

  const int bm = blockIdx.x, bn = blockIdx.y;

  if constexpr (MOE) {
    int total = poff[E_];
    if (bm*TM >= total) return;
    int r0 = bm*TM;
    int eidx = 0;
    #pragma unroll
    for (int e = 0; e < E_; e++) if (r0 >= poff[e+1]) eidx++;
    long eo = (long)eidx * (long)N * (long)ldw;
    Wb += eo;
    if constexpr (FUSED) W3b += eo;
  }

  __shared__ __align__(16) half_t As[2][TM][40];
  __shared__ __align__(16) half_t Bs[2][64][40];
  __shared__ __align__(16) half_t Bs3[FUSED?2:1][FUSED?64:1][FUSED?40:1];

  const int tid  = threadIdx.x;
  const int asr  = tid >> 2;          // staging row 0..63
  const int asc  = (tid & 3) * 8;     // staging k-offset 0/8/16/24
  const int wv   = tid >> 6;
  const int lane = tid & 63;
  const int quad = lane >> 4;
  const int r16  = lane & 15;
  const int wm   = (wv & 1) * (TM/2);
  const int wn   = (wv >> 1) * 32;

  // ---- staging source pointers ----
  const half_t* Ap0; const half_t* Ap1 = nullptr;
  {
    int r0 = bm*TM + asr;
    if constexpr (MODE == GM_MOE13) {
      int tt = tok[r0];
      Ap0 = (tt >= 0) ? (Ab + (long)tt*lda + asc) : nullptr;
    } else {
      Ap0 = (r0 < M) ? (Ab + (long)r0*lda + asc) : nullptr;
    }
    if constexpr (TM == 128) {
      int r1 = bm*TM + 64 + asr;
      if constexpr (MODE == GM_MOE13) {
        int tt = tok[r1];
        Ap1 = (tt >= 0) ? (Ab + (long)tt*lda + asc) : nullptr;
      } else {
        Ap1 = (r1 < M) ? (Ab + (long)r1*lda + asc) : nullptr;
      }
    }
  }
  const int bgn = bn*64 + asr;
  const half_t* Wp  = (bgn < N) ? (Wb + (long)bgn*ldw + asc) : nullptr;
  const half_t* W3p = nullptr;
  if constexpr (FUSED) { if (bgn < N) W3p = W3b + (long)bgn*ldw + asc; }

  HPk ra0, ra1, rb, rb3;
  auto loadT = [&](int k0){
    if (Ap0) { ra0.v = *(const half8*)(Ap0 + k0); }
    else     { for (int j = 0; j < 8; j++) ra0.u[j] = (half_t)0.f; }
    if (TM == 128) {
      if (Ap1) { ra1.v = *(const half8*)(Ap1 + k0); }
      else     { for (int j = 0; j < 8; j++) ra1.u[j] = (half_t)0.f; }
    }
    if (Wp) { rb.v = *(const half8*)(Wp + k0); }
    else    { for (int j = 0; j < 8; j++) rb.u[j] = (half_t)0.f; }
    if (FUSED) {
      if (W3p) { rb3.v = *(const half8*)(W3p + k0); }
      else     { for (int j = 0; j < 8; j++) rb3.u[j] = (half_t)0.f; }
    }
  };
  auto storeT = [&](int buf){
    *(half8*)&As[buf][asr][asc] = ra0.v;
    if (TM == 128) *(half8*)&As[buf][64 + asr][asc] = ra1.v;
    *(half8*)&Bs[buf][asr][asc] = rb.v;
    if (FUSED) *(half8*)&Bs3[buf][asr][asc] = rb3.v;
  };

  floatx4 acc[MFR][2];
  floatx4 acc3[FUSED?MFR:1][FUSED?2:1];
  #pragma unroll
  for (int mi = 0; mi < MFR; mi++)
  #pragma unroll
  for (int ni = 0; ni < 2; ni++){
    acc[mi][ni][0]=0.f; acc[mi][ni][1]=0.f; acc[mi][ni][2]=0.f; acc[mi][ni][3]=0.f;
    if (FUSED){ acc3[mi][ni][0]=0.f; acc3[mi][ni][1]=0.f; acc3[mi][ni][2]=0.f; acc3[mi][ni][3]=0.f; }
  }

  const int nt = Kd >> 5;
  loadT(0);
  storeT(0);
  __syncthreads();

  int cur = 0;
  for (int t = 0; t < nt; ++t) {
    const bool more = (t + 1 < nt);
    if (more) loadT((t + 1) << 5);

    half8 af[MFR];
    #pragma unroll
    for (int mi = 0; mi < MFR; mi++)
      af[mi] = *(const half8*)&As[cur][wm + mi*16 + r16][quad*8];
    half8 bf0 = *(const half8*)&Bs[cur][wn + r16][quad*8];
    half8 bf1 = *(const half8*)&Bs[cur][wn + 16 + r16][quad*8];
    #pragma unroll
    for (int mi = 0; mi < MFR; mi++){
      acc[mi][0] = __builtin_amdgcn_mfma_f32_16x16x32_f16(af[mi], bf0, acc[mi][0], 0,0,0);
      acc[mi][1] = __builtin_amdgcn_mfma_f32_16x16x32_f16(af[mi], bf1, acc[mi][1], 0,0,0);
    }
    if (FUSED) {
      half8 cf0 = *(const half8*)&Bs3[cur][wn + r16][quad*8];
      half8 cf1 = *(const half8*)&Bs3[cur][wn + 16 + r16][quad*8];
      #pragma unroll
      for (int mi = 0; mi < MFR; mi++){
        acc3[mi][0] = __builtin_amdgcn_mfma_f32_16x16x32_f16(af[mi], cf0, acc3[mi][0], 0,0,0);
        acc3[mi][1] = __builtin_amdgcn_mfma_f32_16x16x32_f16(af[mi], cf1, acc3[mi][1], 0,0,0);
      }
    }

    if (more) storeT(cur^1);
    __syncthreads();
    cur ^= 1;
  }

  // ---- epilogue ----
  if constexpr (MODE == GM_QKV) {
    // N tiles: bn 0..11 = q heads (RoPE on wn==32 half); 12..19 = c_kv (f32);
    // bn 20, wn==0 = k_pe (RoPE, shared across heads)
    #pragma unroll
    for (int mi = 0; mi < MFR; mi++)
    #pragma unroll
    for (int i = 0; i < 4; i++) {
      int grow = bm*TM + wm + mi*16 + quad*4 + i;
      int bb = grow >> 9, s = grow & 511;
      float a0 = acc[mi][0][i], a1 = acc[mi][1][i];
      if (bn < 12) {
        half_t* qdst = (half_t*)Cg + (((long)(bb*NH_ + bn))*S_ + s)*64;
        if (wn == 0) {
          qdst[r16]      = f2h(a0 * 0.125f);
          qdst[16 + r16] = f2h(a1 * 0.125f);
        } else {
          float c0 = cosb[s*32 + r16],      sn0 = sinb[s*32 + r16];
          float c1 = cosb[s*32 + 16 + r16], sn1 = sinb[s*32 + 16 + r16];
          qdst[32 + r16] = f2h((a0*c0 - a1*sn0) * 0.125f);
          qdst[48 + r16] = f2h((a1*c1 + a0*sn1) * 0.125f);
        }
      } else if (bn < 20) {
        int cbase = (bn - 12)*64 + wn;
        ckv[(long)grow*512 + cbase + r16]      = a0;
        ckv[(long)grow*512 + cbase + 16 + r16] = a1;
      } else if (wn == 0) {
        float c0 = cosb[s*32 + r16],      sn0 = sinb[s*32 + r16];
        float c1 = cosb[s*32 + 16 + r16], sn1 = sinb[s*32 + 16 + r16];
        kpe[(long)grow*32 + r16]      = f2h(a0*c0 - a1*sn0);
        kpe[(long)grow*32 + 16 + r16] = f2h(a1*c1 + a0*sn1);
      }
    }
    return;
  }

  #pragma unroll
  for (int mi = 0; mi < MFR; mi++)
  #pragma unroll
  for (int ni = 0; ni < 2; ni++)
  #pragma unroll
  for (int i = 0; i < 4; i++) {
    int grow = bm*TM + wm + mi*16 + quad*4 + i;
    int gcol = bn*64 + wn + ni*16 + r16;
    float v = acc[mi][ni][i];
    if (MODE == GM_F32OUT) {
      if (grow < M && gcol < N) {
        float o = v; if (bias) o += bias[gcol];
        ((float*)Cg)[(long)grow*ldc + gcol] = o;
      }
    } else if (MODE == GM_H16OUT) {
      if (grow < M && gcol < N)
        ((half_t*)Cg)[(long)grow*ldc + gcol] = f2h(v);
    } else if (MODE == GM_RESADD) {
      if (grow < M && gcol < N)
        hres[(long)grow*ldc + gcol] += v;
    } else if (MODE == GM_SILU || MODE == GM_MOE13) {
      if (grow < M && gcol < N) {
        float a1 = v, a3 = acc3[mi][ni][i];
        float g = a1 / (1.f + expf(-a1)) * a3;
        ((half_t*)Cg)[(long)grow*ldc + gcol] = f2h(g);
      }
    } else if (MODE == GM_MOE2) {
      int t = tok[grow];
      if (t >= 0) atomicAdd(&hres[(long)t*H_ + gcol], rw[grow]*v);
    }
  }
}

// ---------------- flash attention: one block = (b,h) x 64 q-rows ---------
__global__ __launch_bounds__(256)
void fattn_k(const half_t* __restrict__ Qp, const half_t* __restrict__ kpe,
             const half_t* __restrict__ kvb, half_t* __restrict__ attn){
  const int qb = blockIdx.x;          // q tile 0..7
  const int bh = blockIdx.y;          // b*NH+h
  const int b  = bh / NH_, hh = bh % NH_;
  const int q0 = qb * 64;
  const int nkv = qb + 1;

  __shared__ __align__(16) half_t Qs[64][72];
  __shared__ __align__(16) half_t Ks[64][72];
  __shared__ __align__(16) half_t Vt[64][72];   // V^T: [d][k]
  __shared__ __align__(16) half_t Ps[64][72];

  const int tid = threadIdx.x;
  const int wv = tid >> 6, lane = tid & 63;
  const int quad = lane >> 4, r16 = lane & 15;

  {
    int r = tid >> 2, c = (tid & 3) * 16;
    const half_t* src = Qp + ((long)bh * S_ + q0 + r) * 64 + c;
    *(half8*)&Qs[r][c]   = *(const half8*)(src);
    *(half8*)&Qs[r][c+8] = *(const half8*)(src + 8);
  }
  __syncthreads();

  half8 qf[2];
  qf[0] = *(const half8*)&Qs[wv*16 + r16][quad*8];
  qf[1] = *(const half8*)&Qs[wv*16 + r16][32 + quad*8];

  float m_r[4], l_r[4];
  floatx4 oacc[4];
  #pragma unroll
  for (int i = 0; i < 4; i++){ m_r[i] = -1e30f; l_r[i] = 0.f; }
  #pragma unroll
  for (int no = 0; no < 4; no++){ oacc[no][0]=0.f; oacc[no][1]=0.f; oacc[no][2]=0.f; oacc[no][3]=0.f; }

  const int vr = tid & 63, vc = (tid >> 6) * 16;

  for (int j = 0; j < nkv; ++j) {
    // ---- stage K tile (nope from kvb, pe shared from kpe) + V^T ----
    {
      int r = tid >> 2, c = (tid & 3) * 16;
      if (c < 32) {
        const half_t* ks = kvb + ((long)(b*S_ + j*64 + r))*1152 + hh*96 + c;
        *(half8*)&Ks[r][c]   = *(const half8*)(ks);
        *(half8*)&Ks[r][c+8] = *(const half8*)(ks + 8);
      } else {
        const half_t* ks = kpe + ((long)(b*S_ + j*64 + r))*32 + (c - 32);
        *(half8*)&Ks[r][c]   = *(const half8*)(ks);
        *(half8*)&Ks[r][c+8] = *(const half8*)(ks + 8);
      }
      const half_t* vs = kvb + ((long)(b*S_ + j*64 + vr))*1152 + hh*96 + 32 + vc;
      HPk v0, v1; v0.v = *(const half8*)vs; v1.v = *(const half8*)(vs + 8);
      #pragma unroll
      for (int u = 0; u < 8; u++){ Vt[vc+u][vr] = v0.u[u]; Vt[vc+8+u][vr] = v1.u[u]; }
    }
    __syncthreads();

    floatx4 sacc[4];
    #pragma unroll
    for (int ni = 0; ni < 4; ni++){ sacc[ni][0]=0.f; sacc[ni][1]=0.f; sacc[ni][2]=0.f; sacc[ni][3]=0.f; }
    #pragma unroll
    for (int ks = 0; ks < 2; ks++){
      #pragma unroll
      for (int ni = 0; ni < 4; ni++){
        half8 bf = *(const half8*)&Ks[ni*16 + r16][ks*32 + quad*8];
        sacc[ni] = __builtin_amdgcn_mfma_f32_16x16x32_f16(qf[ks], bf, sacc[ni], 0,0,0);
      }
    }

    #pragma unroll
    for (int i = 0; i < 4; i++){
      int qg = q0 + wv*16 + quad*4 + i;
      #pragma unroll
      for (int ni = 0; ni < 4; ni++){
        int kg = j*64 + ni*16 + r16;
        if (kg > qg) sacc[ni][i] = -1e30f;
      }
    }

    #pragma unroll
    for (int i = 0; i < 4; i++){
      float v = fmaxf(fmaxf(sacc[0][i], sacc[1][i]), fmaxf(sacc[2][i], sacc[3][i]));
      #pragma unroll
      for (int o = 1; o < 16; o <<= 1) v = fmaxf(v, __shfl_xor(v, o, 64));
      float mnew = fmaxf(m_r[i], v);
      float corr = expf(m_r[i] - mnew);
      float ps[4], rs = 0.f;
      #pragma unroll
      for (int ni = 0; ni < 4; ni++){ ps[ni] = expf(sacc[ni][i] - mnew); rs += ps[ni]; }
      #pragma unroll
      for (int o = 1; o < 16; o <<= 1) rs += __shfl_xor(rs, o, 64);
      l_r[i] = l_r[i] * corr + rs;
      m_r[i] = mnew;
      #pragma unroll
      for (int no = 0; no < 4; no++) oacc[no][i] *= corr;
      int row = wv*16 + quad*4 + i;
      #pragma unroll
      for (int ni = 0; ni < 4; ni++) Ps[row][ni*16 + r16] = f2h(ps[ni]);
    }
    __syncthreads();

    #pragma unroll
    for (int ks = 0; ks < 2; ks++){
      half8 paf = *(const half8*)&Ps[wv*16 + r16][ks*32 + quad*8];
      #pragma unroll
      for (int no = 0; no < 4; no++){
        half8 vbf = *(const half8*)&Vt[no*16 + r16][ks*32 + quad*8];
        oacc[no] = __builtin_amdgcn_mfma_f32_16x16x32_f16(paf, vbf, oacc[no], 0,0,0);
      }
    }
    __syncthreads();
  }

  #pragma unroll
  for (int i = 0; i < 4; i++){
    int qg = q0 + wv*16 + quad*4 + i;
    float inv = 1.f / l_r[i];
    #pragma unroll
    for (int no = 0; no < 4; no++){
      int dcol = no*16 + r16;
      attn[((long)(b*S_ + qg))*H_ + hh*64 + dcol] = f2h(oacc[no][i] * inv);
    }
  }
}

// ---------------- conversion: fp32 -> fp16, vectorized ----------------
__global__ void cvt_k(const float* __restrict__ src, half_t* __restrict__ dst, long n){
  long i = ((long)blockIdx.x*256 + threadIdx.x) * 8;
  long stride = (long)gridDim.x * 256 * 8;
  for (; i < n; i += stride){
    float4 a = *(const float4*)(src + i);
    float4 b = *(const float4*)(src + i + 4);
    HPk pk;
    pk.u[0]=f2h(a.x); pk.u[1]=f2h(a.y); pk.u[2]=f2h(a.z); pk.u[3]=f2h(a.w);
    pk.u[4]=f2h(b.x); pk.u[5]=f2h(b.y); pk.u[6]=f2h(b.z); pk.u[7]=f2h(b.w);
    *(half8*)(dst + i) = pk.v;
  }
}

__global__ void cvt_off_k(const float* __restrict__ src, half_t* __restrict__ dst,
                          long chunk, long dstStride, long dstOff, long total){
  long i = ((long)blockIdx.x*256 + threadIdx.x) * 8;
  long stride = (long)gridDim.x * 256 * 8;
  for (; i < total; i += stride){
    long l = i / chunk, r = i - l*chunk;
    float4 a = *(const float4*)(src + i);
    float4 b = *(const float4*)(src + i + 4);
    HPk pk;
    pk.u[0]=f2h(a.x); pk.u[1]=f2h(a.y); pk.u[2]=f2h(a.z); pk.u[3]=f2h(a.w);
    pk.u[4]=f2h(b.x); pk.u[5]=f2h(b.y); pk.u[6]=f2h(b.z); pk.u[7]=f2h(b.w);
    *(half8*)(dst + l*dstStride + dstOff + r) = pk.v;
  }
}

// ---------------- fused rms-normalize ----------------
__global__ void normh_k(const float* __restrict__ x, int ld, int n,
                        const float* __restrict__ w, half_t* __restrict__ out){
  int t = blockIdx.x;
  const float* p = x + (long)t*ld;
  float s = 0.f;
  for (int i = threadIdx.x; i < n; i += 256){ float v = p[i]; s += v*v; }
  s = blockReduceSum256(s);
  float rs = rsqrtf(s/(float)n + 1e-6f);
  half_t* o = out + (long)t*n;
  for (int i = threadIdx.x; i < n; i += 256) o[i] = f2h(p[i]*rs*w[i]);
}

// ---------------- fused rms-normalize + MoE gate top-2 ----------------
__global__ void normgate_k(const float* __restrict__ x,
                           const float* __restrict__ mnw,
                           const float* __restrict__ gw,
                           half_t* __restrict__ xm,
                           int* __restrict__ topi, float* __restrict__ topv){
  int t = blockIdx.x;
  int tid = threadIdx.x;
  int wv = tid >> 6, lane = tid & 63;
  const float* p = x + (long)t*H_;
  float s = 0.f;
  for (int i = tid; i < H_; i += 256){ float v = p[i]; s += v*v; }
  s = blockReduceSum256(s);
  float rs = rsqrtf(s/(float)H_ + 1e-6f);
  half_t* o = xm + (long)t*H_;
  float acc[E_];
  #pragma unroll
  for (int e = 0; e < E_; e++) acc[e] = 0.f;
  for (int i = tid; i < H_; i += 256){
    float xv = p[i]*rs*mnw[i];
    o[i] = f2h(xv);
    #pragma unroll
    for (int e = 0; e < E_; e++) acc[e] += xv * gw[e*H_ + i];
  }
  __shared__ float lsum[E_][4];
  #pragma unroll
  for (int e = 0; e < E_; e++){
    float v = acc[e];
    #pragma unroll
    for (int o2 = 32; o2 > 0; o2 >>= 1) v += __shfl_down(v, o2, 64);
    if (lane == 0) lsum[e][wv] = v;
  }
  __syncthreads();
  if (tid == 0){
    float logits[E_];
    #pragma unroll
    for (int e = 0; e < E_; e++) logits[e] = lsum[e][0]+lsum[e][1]+lsum[e][2]+lsum[e][3];
    int i0 = 0; float m0 = -1e30f;
    for (int e = 0; e < E_; e++) if (logits[e] > m0){ m0 = logits[e]; i0 = e; }
    int i1 = 0; float m1 = -1e30f;
    for (int e = 0; e < E_; e++) if (e != i0 && logits[e] > m1){ m1 = logits[e]; i1 = e; }
    float e1 = expf(m1 - m0); float z = 1.f + e1;
    topi[t*2] = i0; topi[t*2+1] = i1;
    topv[t*2] = 1.f/z; topv[t*2+1] = e1/z;
  }
}

// ---------------- small kernels ----------------
__global__ void rope_tab_k(float* cosb, float* sinb){ // grid S_, block 32
  int s = blockIdx.x, d = threadIdx.x;
  float inv = powf(10000.f, -(float)(2*d)/(2.f*DR_));
  float f = (float)s * inv;
  cosb[s*32+d] = cosf(f);
  sinb[s*32+d] = sinf(f);
}

__global__ void route_k(const int* __restrict__ topi, const float* __restrict__ topv,
                        int* __restrict__ poff, int* __restrict__ tok, float* __restrict__ rw){
  __shared__ int cnt[8], fill[8], off_s[9];
  int tid = threadIdx.x;
  if (tid < 8){ cnt[tid] = 0; fill[tid] = 0; }
  __syncthreads();
  atomicAdd(&cnt[topi[tid*2]], 1);
  atomicAdd(&cnt[topi[tid*2+1]], 1);
  __syncthreads();
  if (tid == 0){
    int o = 0;
    for (int e = 0; e < E_; e++){ off_s[e] = o; o += (cnt[e] + 63) & ~63; }
    off_s[E_] = o;
    for (int e = 0; e <= E_; e++) poff[e] = off_s[e];
  }
  __syncthreads();
  for (int i = tid; i < MOECAP; i += 1024){ tok[i] = -1; rw[i] = 0.f; }
  __syncthreads();
  #pragma unroll
  for (int j = 0; j < 2; j++){
    int e = topi[tid*2+j];
    int pos = atomicAdd(&fill[e], 1);
    int idx = off_s[e] + pos;
    tok[idx] = tid; rw[idx] = topv[tid*2+j];
  }
}

__global__ void head_k(const float* __restrict__ h, const float* __restrict__ fnw,
                       const float* __restrict__ hw, const float* __restrict__ hb,
                       float* __restrict__ out){
  int b = blockIdx.x; int t = b*S_ + S_ - 1;
  const float* hp = h + (long)t*H_;
  float ss = 0.f;
  for (int j = threadIdx.x; j < H_; j += 256){ float v = hp[j]; ss += v*v; }
  ss = blockReduceSum256(ss);
  __shared__ float rs_s;
  if (threadIdx.x == 0) rs_s = rsqrtf(ss/(float)H_ + 1e-6f);
  __syncthreads();
  float rs = rs_s;
  float d = 0.f;
  for (int j = threadIdx.x; j < H_; j += 256) d += hp[j]*rs*fnw[j]*hw[j];
  d = blockReduceSum256(d);
  if (threadIdx.x == 0) out[b] = d + hb[0];
}

// ---------------- host ----------------
extern "C" void kernel_launch(void* const* d_in, const int* in_sizes, int n_in,
                              void* d_out, int out_size, void* d_ws, size_t ws_size,
                              hipStream_t stream) {
  const float* inputs = (const float*)d_in[0];
  const float* in_w   = (const float*)d_in[1];
  const float* in_b   = (const float*)d_in[2];
  const float* anw_a  = (const float*)d_in[3];
  const float* wq_a   = (const float*)d_in[4];
  const float* wkva_a = (const float*)d_in[5];
  const float* kvn_a  = (const float*)d_in[6];
  const float* wkvb_a = (const float*)d_in[7];
  const float* wo_a   = (const float*)d_in[8];
  const float* mnw_a  = (const float*)d_in[9];
  const float* gw_a   = (const float*)d_in[10];
  const float* w1_a   = (const float*)d_in[11];
  const float* w2_a   = (const float*)d_in[12];
  const float* w3_a   = (const float*)d_in[13];
  const float* sw1_a  = (const float*)d_in[14];
  const float* sw2_a  = (const float*)d_in[15];
  const float* sw3_a  = (const float*)d_in[16];
  const float* fnw    = (const float*)d_in[17];
  const float* hw     = (const float*)d_in[18];
  const float* hb     = (const float*)d_in[19];
  (void)in_sizes; (void)n_in; (void)out_size;

  char* p = (char*)d_ws;
  auto alloc = [&](size_t bytes)->char*{
    char* r = p; p += (bytes + 255) & ~(size_t)255; return r;
  };
  // ---- activations ----
  float*  h_      = (float*) alloc((size_t)T_*H_*4);
  float*  ckv_    = (float*) alloc((size_t)T_*512*4);
  half_t* kvb_    = (half_t*)alloc((size_t)T_*1152*2);
  half_t* Qp_     = (half_t*)alloc((size_t)B_*NH_*S_*64*2);
  half_t* Kpe_    = (half_t*)alloc((size_t)T_*32*2);
  half_t* attn_   = (half_t*)alloc((size_t)T_*H_*2);
  half_t* g_      = (half_t*)alloc((size_t)MOECAP*I_*2);
  half_t* gs_     = (half_t*)alloc((size_t)T_*SI_*2);
  half_t* xh_     = (half_t*)alloc((size_t)T_*H_*2);     // rms(h)*anw  fp16
  half_t* xm_     = (half_t*)alloc((size_t)T_*H_*2);     // rms(h)*mnw  fp16
  half_t* ckvh_   = (half_t*)alloc((size_t)T_*R_*2);     // rms(c_kv)*kvn fp16
  half_t* inh_    = (half_t*)alloc((size_t)T_*64*2);     // inputs fp16
  half_t* inwh_   = (half_t*)alloc((size_t)768*64*2);    // in_w fp16
  float*  cosb_   = (float*) alloc((size_t)S_*32*4);
  float*  sinb_   = (float*) alloc((size_t)S_*32*4);
  float*  topv_   = (float*) alloc((size_t)T_*2*4);
  int*    topi_   = (int*)   alloc((size_t)T_*2*4);
  int*    poff_   = (int*)   alloc(64);
  int*    tok_    = (int*)   alloc((size_t)MOECAP*4);
  float*  rw_     = (float*) alloc((size_t)MOECAP*4);

  // ---- fp16 weight image ----
  const size_t nWQ1   = (size_t)768*H_;
  const size_t nWKVA1 = (size_t)544*H_;
  const size_t nQKV1  = (size_t)NQKV*H_;
  const size_t nWKVB1 = (size_t)1152*R_;
  const size_t nWO1   = (size_t)H_*768;
  const size_t nE1    = (size_t)E_*I_*H_;
  const size_t nSW1   = (size_t)SI_*H_;
  const size_t perLayer = nQKV1+nWKVB1+nWO1+3*nE1+3*nSW1;
  const size_t allw = (size_t)L_ * perLayer * 2;
  size_t usedAct = (size_t)(p - (char*)d_ws);
  bool big = (ws_size == 0) || (usedAct + allw + (size_t)(1u<<20) <= ws_size);

  half_t *qkvW,*wkvbW,*woW,*e1W,*e2W,*e3W,*sw1W,*sw2W,*sw3W;
  if (big){
    qkvW  = (half_t*)alloc((size_t)L_*nQKV1*2);
    wkvbW = (half_t*)alloc((size_t)L_*nWKVB1*2);
    woW   = (half_t*)alloc((size_t)L_*nWO1*2);
    e1W   = (half_t*)alloc((size_t)L_*nE1*2);
    e2W   = (half_t*)alloc((size_t)L_*nE1*2);
    e3W   = (half_t*)alloc((size_t)L_*nE1*2);
    sw1W  = (half_t*)alloc((size_t)L_*nSW1*2);
    sw2W  = (half_t*)alloc((size_t)L_*nSW1*2);
    sw3W  = (half_t*)alloc((size_t)L_*nSW1*2);
  } else {
    qkvW  = (half_t*)alloc(nQKV1*2);
    wkvbW = (half_t*)alloc(nWKVB1*2);
    woW   = (half_t*)alloc(nWO1*2);
    e1W   = (half_t*)alloc(nE1*2);
    e2W   = (half_t*)alloc(nE1*2);
    e3W   = (half_t*)alloc(nE1*2);
    sw1W  = (half_t*)alloc(nSW1*2);
    sw2W  = (half_t*)alloc(nSW1*2);
    sw3W  = (half_t*)alloc(nSW1*2);
  }

  auto cvt = [&](const float* s, half_t* d, size_t n){
    long blocks = (long)((n/8 + 255) / 256);
    int grid = (int)(blocks > 2048 ? 2048 : blocks);
    cvt_k<<<grid, 256, 0, stream>>>(s, d, (long)n);
  };
  auto cvt_off = [&](const float* s, half_t* d, size_t chunk, size_t dstStride,
                     size_t dstOff, size_t total){
    long blocks = (long)((total/8 + 255) / 256);
    int grid = (int)(blocks > 2048 ? 2048 : blocks);
    cvt_off_k<<<grid, 256, 0, stream>>>(s, d, (long)chunk, (long)dstStride,
                                        (long)dstOff, (long)total);
  };

  cvt(inputs, inh_, (size_t)T_*64);
  cvt(in_w,   inwh_,(size_t)768*64);
  if (big){
    cvt_off(wq_a,   qkvW, nWQ1,   nQKV1, 0,     (size_t)L_*nWQ1);
    cvt_off(wkva_a, qkvW, nWKVA1, nQKV1, nWQ1,  (size_t)L_*nWKVA1);
    cvt(wkvb_a, wkvbW, (size_t)L_*nWKVB1);
    cvt(wo_a,   woW,   (size_t)L_*nWO1);
    cvt(w1_a,   e1W,   (size_t)L_*nE1);
    cvt(w2_a,   e2W,   (size_t)L_*nE1);
    cvt(w3_a,   e3W,   (size_t)L_*nE1);
    cvt(sw1_a,  sw1W,  (size_t)L_*nSW1);
    cvt(sw2_a,  sw2W,  (size_t)L_*nSW1);
    cvt(sw3_a,  sw3W,  (size_t)L_*nSW1);
  }

  rope_tab_k<<<S_, 32, 0, stream>>>(cosb_, sinb_);

  #define GEMM_TAIL nullptr,nullptr,nullptr,nullptr,nullptr,nullptr,nullptr,nullptr,nullptr
  gemm_k<GM_F32OUT,128><<<dim3(8,12,1), 256, 0, stream>>>(
      inh_,64, inwh_,64, nullptr, h_,768, T_,768,64,
      in_b, nullptr,nullptr,nullptr,nullptr, nullptr,nullptr,nullptr,nullptr);

  for (int l = 0; l < L_; l++) {
    const float* anw  = anw_a  + (size_t)l*H_;
    const float* kvn  = kvn_a  + (size_t)l*R_;
    const float* mnw  = mnw_a  + (size_t)l*H_;
    const float* gw_l = gw_a   + (size_t)l*E_*H_;

    const half_t* qkvh  = big ? qkvW  + (size_t)l*nQKV1  : qkvW;
    const half_t* wkvbh = big ? wkvbW + (size_t)l*nWKVB1 : wkvbW;
    const half_t* woh   = big ? woW   + (size_t)l*nWO1   : woW;
    const half_t* e1h   = big ? e1W   + (size_t)l*nE1    : e1W;
    const half_t* e2h   = big ? e2W   + (size_t)l*nE1    : e2W;
    const half_t* e3h   = big ? e3W   + (size_t)l*nE1    : e3W;
    const half_t* sw1h  = big ? sw1W  + (size_t)l*nSW1   : sw1W;
    const half_t* sw2h  = big ? sw2W  + (size_t)l*nSW1   : sw2W;
    const half_t* sw3h  = big ? sw3W  + (size_t)l*nSW1   : sw3W;

    if (!big){
      cvt(wq_a   + (size_t)l*nWQ1,   qkvW,         nWQ1);
      cvt(wkva_a + (size_t)l*nWKVA1, qkvW + nWQ1,  nWKVA1);
      cvt(wkvb_a + (size_t)l*nWKVB1, wkvbW, nWKVB1);
      cvt(wo_a   + (size_t)l*nWO1,   woW,   nWO1);
      cvt(w1_a   + (size_t)l*nE1,    e1W,   nE1);
      cvt(w2_a   + (size_t)l*nE1,    e2W,   nE1);
      cvt(w3_a   + (size_t)l*nE1,    e3W,   nE1);
      cvt(sw1_a  + (size_t)l*nSW1,   sw1W,  nSW1);
      cvt(sw2_a  + (size_t)l*nSW1,   sw2W,  nSW1);
      cvt(sw3_a  + (size_t)l*nSW1,   sw3W,  nSW1);
    }

    // ---- attention ----
    normh_k<<<T_, 256, 0, stream>>>(h_, H_, H_, anw, xh_);
    // fused QKV projection + in-epilogue RoPE: writes Qp (fp16, scaled),
    // ckv (f32), Kpe (fp16, roped)
    gemm_k<GM_QKV,128><<<dim3(8,21,1), 256, 0, stream>>>(
        xh_,H_, qkvh,H_, nullptr, Qp_,0, T_,NQKV,H_,
        nullptr, nullptr,nullptr,nullptr,nullptr,
        cosb_, sinb_, Kpe_, ckv_);
    normh_k<<<T_, 256, 0, stream>>>(ckv_, 512, R_, kvn, ckvh_);
    gemm_k<GM_H16OUT,128><<<dim3(8,18,1), 256, 0, stream>>>(
        ckvh_,R_, wkvbh,R_, nullptr, kvb_,1152, T_,1152,R_,
        nullptr, nullptr,nullptr,nullptr,nullptr, nullptr,nullptr,nullptr,nullptr);
    fattn_k<<<dim3(S_/64, B_*NH_), 256, 0, stream>>>(Qp_, Kpe_, kvb_, attn_);
    gemm_k<GM_RESADD,128><<<dim3(8,12,1), 256, 0, stream>>>(
        attn_,H_, woh,768, nullptr, nullptr,H_, T_,H_,768,
        nullptr, h_, nullptr,nullptr,nullptr, nullptr,nullptr,nullptr,nullptr);

    // ---- MoE + shared expert ----
    normgate_k<<<T_, 256, 0, stream>>>(h_, mnw, gw_l, xm_, topi_, topv_);
    route_k<<<1, 1024, 0, stream>>>(topi_, topv_, poff_, tok_, rw_);
    gemm_k<GM_SILU,128><<<dim3(8,16,1), 256, 0, stream>>>(
        xm_,H_, sw1h,H_, sw3h, gs_,SI_, T_,SI_,H_,
        nullptr, nullptr,nullptr,nullptr,nullptr, nullptr,nullptr,nullptr,nullptr);
    gemm_k<GM_MOE13,64><<<dim3(MOECAP/64,4,1), 256, 0, stream>>>(
        xm_,H_, e1h,H_, e3h, g_,I_, MOECAP,I_,H_,
        nullptr, nullptr, tok_, rw_, poff_, nullptr,nullptr,nullptr,nullptr);
    gemm_k<GM_MOE2,64><<<dim3(MOECAP/64,12,1), 256, 0, stream>>>(
        g_,I_, e2h,I_, nullptr, nullptr,H_, MOECAP,H_,I_,
        nullptr, h_, tok_, rw_, poff_, nullptr,nullptr,nullptr,nullptr);
    gemm_k<GM_RESADD,128><<<dim3(8,12,1), 256, 0, stream>>>(
        gs_,SI_, sw2h,SI_, nullptr, nullptr,H_, T_,H_,SI_,
        nullptr, h_, nullptr,nullptr,nullptr, nullptr,nullptr,nullptr,nullptr);
  }

  head_k<<<B_, 256, 0, stream>>>(h_, fnw, hw, hb, (float*)d_out);
}

// Round 6
// 1867.847 us; speedup vs baseline: 1.3538x; 1.3538x over previous
//
#include <hip/hip_runtime.h>
#include <cstdint>
#include <cmath>

#define L_ 12
#define H_ 768
#define NH_ 12
#define DN_ 32
#define DR_ 32
#define DV_ 64
#define R_ 512
#define E_ 8
#define I_ 256
#define SI_ 1024
#define B_ 2
#define S_ 512
#define T_ (B_*S_)
#define MOECAP 2560   // 2048 rows + up to 8*63 pad, rounded
#define NQKV 1312     // 768 (wq) + 544 (wkva) fused

typedef _Float16 half_t;
typedef __attribute__((ext_vector_type(8))) _Float16 half8;
typedef __attribute__((ext_vector_type(4))) float floatx4;

union HPk { half8 v; half_t u[8]; };

__device__ inline half_t f2h(float f){ return (half_t)f; }
__device__ inline float h2f(half_t h){ return (float)h; }

__device__ inline float blockReduceSum256(float v){
  __shared__ float red[4];
  float w = v;
  #pragma unroll
  for (int o = 32; o > 0; o >>= 1) w += __shfl_down(w, o, 64);
  __syncthreads();
  if ((threadIdx.x & 63) == 0) red[threadIdx.x >> 6] = w;
  __syncthreads();
  return red[0] + red[1] + red[2] + red[3];
}

// ---------------- GEMM: C[M,N] = A[M,K] * W[N,K]^T, fp16 in, fp32 acc ----
// 64x64 tile, BK=64 double-buffered (one barrier per 64-K), dynamic LDS.
enum { GM_F32OUT=0, GM_H16OUT=1, GM_QKV=2, GM_RESADD=4, GM_RESADDA=5,
       GM_SILU=6, GM_MOE13=7, GM_MOE2=8 };

struct GArgs {
  const half_t* Ab; int lda;
  const half_t* Wb; int ldw;
  const half_t* W3b;
  void* Cg; int ldc;
  int M, N, Kd;
  const float* bias;
  float* hres;
  const int* tok;
  const float* rw;
  const int* poff;
  const float* cosb; const float* sinb;
  half_t* kpe; float* ckv;
};

#define SM_NF 36864   // As + Bs      (2 bufs x 64 x 72 halfs each)
#define SM_F  55296   // + Bs3

template<int MODE>
__device__ __forceinline__ void gemm_body(char* smem, const GArgs& g, int bm, int bn)
{
  constexpr bool FUSED = (MODE==GM_SILU || MODE==GM_MOE13);
  constexpr bool MOE   = (MODE==GM_MOE13 || MODE==GM_MOE2);

  if (bm*64 >= g.M) return;

  const half_t* Ab  = g.Ab;
  const half_t* Wb  = g.Wb;
  const half_t* W3b = g.W3b;

  if constexpr (MOE) {
    int total = g.poff[E_];
    if (bm*64 >= total) return;
    int r0 = bm*64;
    int eidx = 0;
    #pragma unroll
    for (int e = 0; e < E_; e++) if (r0 >= g.poff[e+1]) eidx++;
    long eo = (long)eidx * (long)g.N * (long)g.ldw;
    Wb += eo;
    if constexpr (FUSED) W3b += eo;
  }

  half_t (*As)[72]  = (half_t(*)[72])(smem);
  half_t (*Bs)[72]  = (half_t(*)[72])(smem + 18432);
  half_t (*Bs3)[72] = (half_t(*)[72])(smem + 36864);

  const int tid  = threadIdx.x;
  const int asr  = tid >> 2;          // staging row 0..63
  const int asc  = (tid & 3) * 16;    // staging k-offset 0/16/32/48
  const int wv   = tid >> 6;
  const int lane = tid & 63;
  const int quad = lane >> 4;
  const int r16  = lane & 15;
  const int wm   = (wv & 1) * 32;
  const int wn   = (wv >> 1) * 32;

  const half_t* Ap = nullptr;
  {
    int r0 = bm*64 + asr;
    if constexpr (MODE == GM_MOE13) {
      int tt = g.tok[r0];
      if (tt >= 0) Ap = Ab + (long)tt*g.lda + asc;
    } else {
      if (r0 < g.M) Ap = Ab + (long)r0*g.lda + asc;
    }
  }
  const int bgn = bn*64 + asr;
  const half_t* Wp  = (bgn < g.N) ? (Wb + (long)bgn*g.ldw + asc) : nullptr;
  const half_t* W3p = nullptr;
  if constexpr (FUSED) { if (bgn < g.N) W3p = W3b + (long)bgn*g.ldw + asc; }

  HPk raa, rab, rba, rbb, r3a, r3b;
  auto loadT = [&](int k0){
    if (Ap) { raa.v = *(const half8*)(Ap + k0); rab.v = *(const half8*)(Ap + k0 + 8); }
    else { for (int j=0;j<8;j++){ raa.u[j]=(half_t)0.f; rab.u[j]=(half_t)0.f; } }
    if (Wp) { rba.v = *(const half8*)(Wp + k0); rbb.v = *(const half8*)(Wp + k0 + 8); }
    else { for (int j=0;j<8;j++){ rba.u[j]=(half_t)0.f; rbb.u[j]=(half_t)0.f; } }
    if (FUSED) {
      if (W3p) { r3a.v = *(const half8*)(W3p + k0); r3b.v = *(const half8*)(W3p + k0 + 8); }
      else { for (int j=0;j<8;j++){ r3a.u[j]=(half_t)0.f; r3b.u[j]=(half_t)0.f; } }
    }
  };
  auto storeT = [&](int buf){
    *(half8*)&As[buf*64 + asr][asc]     = raa.v;
    *(half8*)&As[buf*64 + asr][asc + 8] = rab.v;
    *(half8*)&Bs[buf*64 + asr][asc]     = rba.v;
    *(half8*)&Bs[buf*64 + asr][asc + 8] = rbb.v;
    if (FUSED) {
      *(half8*)&Bs3[buf*64 + asr][asc]     = r3a.v;
      *(half8*)&Bs3[buf*64 + asr][asc + 8] = r3b.v;
    }
  };

  floatx4 acc[2][2];
  floatx4 acc3[FUSED?2:1][FUSED?2:1];
  #pragma unroll
  for (int mi = 0; mi < 2; mi++)
  #pragma unroll
  for (int ni = 0; ni < 2; ni++){
    acc[mi][ni][0]=0.f; acc[mi][ni][1]=0.f; acc[mi][ni][2]=0.f; acc[mi][ni][3]=0.f;
    if (FUSED){ acc3[mi][ni][0]=0.f; acc3[mi][ni][1]=0.f; acc3[mi][ni][2]=0.f; acc3[mi][ni][3]=0.f; }
  }

  const int nt = g.Kd >> 6;
  loadT(0);
  storeT(0);
  __syncthreads();

  int cur = 0;
  for (int t = 0; t < nt; ++t) {
    const bool more = (t + 1 < nt);
    if (more) loadT((t + 1) << 6);

    #pragma unroll
    for (int ks = 0; ks < 2; ks++){
      half8 af0 = *(const half8*)&As[cur*64 + wm + r16][ks*32 + quad*8];
      half8 af1 = *(const half8*)&As[cur*64 + wm + 16 + r16][ks*32 + quad*8];
      half8 bf0 = *(const half8*)&Bs[cur*64 + wn + r16][ks*32 + quad*8];
      half8 bf1 = *(const half8*)&Bs[cur*64 + wn + 16 + r16][ks*32 + quad*8];
      acc[0][0] = __builtin_amdgcn_mfma_f32_16x16x32_f16(af0, bf0, acc[0][0], 0,0,0);
      acc[0][1] = __builtin_amdgcn_mfma_f32_16x16x32_f16(af0, bf1, acc[0][1], 0,0,0);
      acc[1][0] = __builtin_amdgcn_mfma_f32_16x16x32_f16(af1, bf0, acc[1][0], 0,0,0);
      acc[1][1] = __builtin_amdgcn_mfma_f32_16x16x32_f16(af1, bf1, acc[1][1], 0,0,0);
      if (FUSED) {
        half8 cf0 = *(const half8*)&Bs3[cur*64 + wn + r16][ks*32 + quad*8];
        half8 cf1 = *(const half8*)&Bs3[cur*64 + wn + 16 + r16][ks*32 + quad*8];
        acc3[0][0] = __builtin_amdgcn_mfma_f32_16x16x32_f16(af0, cf0, acc3[0][0], 0,0,0);
        acc3[0][1] = __builtin_amdgcn_mfma_f32_16x16x32_f16(af0, cf1, acc3[0][1], 0,0,0);
        acc3[1][0] = __builtin_amdgcn_mfma_f32_16x16x32_f16(af1, cf0, acc3[1][0], 0,0,0);
        acc3[1][1] = __builtin_amdgcn_mfma_f32_16x16x32_f16(af1, cf1, acc3[1][1], 0,0,0);
      }
    }

    if (more) storeT(cur^1);
    __syncthreads();
    cur ^= 1;
  }

  // ---- epilogue ----
  if constexpr (MODE == GM_QKV) {
    // bn 0..11 = q heads (RoPE on wn==32 half); 12..19 = c_kv (f32);
    // bn 20, wn==0 = k_pe (RoPE, shared across heads)
    #pragma unroll
    for (int mi = 0; mi < 2; mi++)
    #pragma unroll
    for (int i = 0; i < 4; i++) {
      int grow = bm*64 + wm + mi*16 + quad*4 + i;
      int bb = grow >> 9, s = grow & 511;
      float a0 = acc[mi][0][i], a1 = acc[mi][1][i];
      if (bn < 12) {
        half_t* qdst = (half_t*)g.Cg + (((long)(bb*NH_ + bn))*S_ + s)*64;
        if (wn == 0) {
          qdst[r16]      = f2h(a0 * 0.125f);
          qdst[16 + r16] = f2h(a1 * 0.125f);
        } else {
          float c0 = g.cosb[s*32 + r16],      sn0 = g.sinb[s*32 + r16];
          float c1 = g.cosb[s*32 + 16 + r16], sn1 = g.sinb[s*32 + 16 + r16];
          qdst[32 + r16] = f2h((a0*c0 - a1*sn0) * 0.125f);
          qdst[48 + r16] = f2h((a1*c1 + a0*sn1) * 0.125f);
        }
      } else if (bn < 20) {
        int cbase = (bn - 12)*64 + wn;
        g.ckv[(long)grow*512 + cbase + r16]      = a0;
        g.ckv[(long)grow*512 + cbase + 16 + r16] = a1;
      } else if (wn == 0) {
        float c0 = g.cosb[s*32 + r16],      sn0 = g.sinb[s*32 + r16];
        float c1 = g.cosb[s*32 + 16 + r16], sn1 = g.sinb[s*32 + 16 + r16];
        g.kpe[(long)grow*32 + r16]      = f2h(a0*c0 - a1*sn0);
        g.kpe[(long)grow*32 + 16 + r16] = f2h(a1*c1 + a0*sn1);
      }
    }
    return;
  }

  #pragma unroll
  for (int mi = 0; mi < 2; mi++)
  #pragma unroll
  for (int ni = 0; ni < 2; ni++)
  #pragma unroll
  for (int i = 0; i < 4; i++) {
    int grow = bm*64 + wm + mi*16 + quad*4 + i;
    int gcol = bn*64 + wn + ni*16 + r16;
    float v = acc[mi][ni][i];
    if (MODE == GM_F32OUT) {
      if (grow < g.M && gcol < g.N) {
        float o = v; if (g.bias) o += g.bias[gcol];
        ((float*)g.Cg)[(long)grow*g.ldc + gcol] = o;
      }
    } else if (MODE == GM_H16OUT) {
      if (grow < g.M && gcol < g.N)
        ((half_t*)g.Cg)[(long)grow*g.ldc + gcol] = f2h(v);
    } else if (MODE == GM_RESADD) {
      if (grow < g.M && gcol < g.N)
        g.hres[(long)grow*g.ldc + gcol] += v;
    } else if (MODE == GM_RESADDA) {
      if (grow < g.M && gcol < g.N)
        atomicAdd(&g.hres[(long)grow*g.ldc + gcol], v);
    } else if (MODE == GM_SILU || MODE == GM_MOE13) {
      if (grow < g.M && gcol < g.N) {
        float a1 = v, a3 = acc3[mi][ni][i];
        float gg = a1 / (1.f + expf(-a1)) * a3;
        ((half_t*)g.Cg)[(long)grow*g.ldc + gcol] = f2h(gg);
      }
    } else if (MODE == GM_MOE2) {
      int t = g.tok[grow];
      if (t >= 0) atomicAdd(&g.hres[(long)t*H_ + gcol], g.rw[grow]*v);
    }
  }
}

template<int MODE>
__global__ __launch_bounds__(256)
void gemm_k(GArgs g){
  extern __shared__ char smem[];
  gemm_body<MODE>(smem, g, blockIdx.x, blockIdx.y);
}

template<int MA, int MB>
__global__ __launch_bounds__(256)
void gemm2_k(GArgs a, GArgs b, int splitY){
  extern __shared__ char smem[];
  if ((int)blockIdx.y < splitY) gemm_body<MA>(smem, a, blockIdx.x, blockIdx.y);
  else                          gemm_body<MB>(smem, b, blockIdx.x, blockIdx.y - splitY);
}

// ---------------- flash attention: one block = (b,h) x 64 q-rows ---------
__global__ __launch_bounds__(256)
void fattn_k(const half_t* __restrict__ Qp, const half_t* __restrict__ kpe,
             const half_t* __restrict__ kvb, half_t* __restrict__ attn){
  const int qb = blockIdx.x;          // q tile 0..7
  const int bh = blockIdx.y;          // b*NH+h
  const int b  = bh / NH_, hh = bh % NH_;
  const int q0 = qb * 64;
  const int nkv = qb + 1;

  __shared__ __align__(16) half_t Qs[64][72];
  __shared__ __align__(16) half_t Ks[64][72];
  __shared__ __align__(16) half_t Vt[64][72];   // V^T: [d][k]
  __shared__ __align__(16) half_t Ps[64][72];

  const int tid = threadIdx.x;
  const int wv = tid >> 6, lane = tid & 63;
  const int quad = lane >> 4, r16 = lane & 15;

  {
    int r = tid >> 2, c = (tid & 3) * 16;
    const half_t* src = Qp + ((long)bh * S_ + q0 + r) * 64 + c;
    *(half8*)&Qs[r][c]   = *(const half8*)(src);
    *(half8*)&Qs[r][c+8] = *(const half8*)(src + 8);
  }
  __syncthreads();

  half8 qf[2];
  qf[0] = *(const half8*)&Qs[wv*16 + r16][quad*8];
  qf[1] = *(const half8*)&Qs[wv*16 + r16][32 + quad*8];

  float m_r[4], l_r[4];
  floatx4 oacc[4];
  #pragma unroll
  for (int i = 0; i < 4; i++){ m_r[i] = -1e30f; l_r[i] = 0.f; }
  #pragma unroll
  for (int no = 0; no < 4; no++){ oacc[no][0]=0.f; oacc[no][1]=0.f; oacc[no][2]=0.f; oacc[no][3]=0.f; }

  const int vr = tid & 63, vc = (tid >> 6) * 16;

  for (int j = 0; j < nkv; ++j) {
    {
      int r = tid >> 2, c = (tid & 3) * 16;
      if (c < 32) {
        const half_t* ks = kvb + ((long)(b*S_ + j*64 + r))*1152 + hh*96 + c;
        *(half8*)&Ks[r][c]   = *(const half8*)(ks);
        *(half8*)&Ks[r][c+8] = *(const half8*)(ks + 8);
      } else {
        const half_t* ks = kpe + ((long)(b*S_ + j*64 + r))*32 + (c - 32);
        *(half8*)&Ks[r][c]   = *(const half8*)(ks);
        *(half8*)&Ks[r][c+8] = *(const half8*)(ks + 8);
      }
      const half_t* vs = kvb + ((long)(b*S_ + j*64 + vr))*1152 + hh*96 + 32 + vc;
      HPk v0, v1; v0.v = *(const half8*)vs; v1.v = *(const half8*)(vs + 8);
      #pragma unroll
      for (int u = 0; u < 8; u++){ Vt[vc+u][vr] = v0.u[u]; Vt[vc+8+u][vr] = v1.u[u]; }
    }
    __syncthreads();

    floatx4 sacc[4];
    #pragma unroll
    for (int ni = 0; ni < 4; ni++){ sacc[ni][0]=0.f; sacc[ni][1]=0.f; sacc[ni][2]=0.f; sacc[ni][3]=0.f; }
    #pragma unroll
    for (int ks = 0; ks < 2; ks++){
      #pragma unroll
      for (int ni = 0; ni < 4; ni++){
        half8 bf = *(const half8*)&Ks[ni*16 + r16][ks*32 + quad*8];
        sacc[ni] = __builtin_amdgcn_mfma_f32_16x16x32_f16(qf[ks], bf, sacc[ni], 0,0,0);
      }
    }

    #pragma unroll
    for (int i = 0; i < 4; i++){
      int qg = q0 + wv*16 + quad*4 + i;
      #pragma unroll
      for (int ni = 0; ni < 4; ni++){
        int kg = j*64 + ni*16 + r16;
        if (kg > qg) sacc[ni][i] = -1e30f;
      }
    }

    #pragma unroll
    for (int i = 0; i < 4; i++){
      float v = fmaxf(fmaxf(sacc[0][i], sacc[1][i]), fmaxf(sacc[2][i], sacc[3][i]));
      #pragma unroll
      for (int o = 1; o < 16; o <<= 1) v = fmaxf(v, __shfl_xor(v, o, 64));
      float mnew = fmaxf(m_r[i], v);
      float corr = expf(m_r[i] - mnew);
      float ps[4], rs = 0.f;
      #pragma unroll
      for (int ni = 0; ni < 4; ni++){ ps[ni] = expf(sacc[ni][i] - mnew); rs += ps[ni]; }
      #pragma unroll
      for (int o = 1; o < 16; o <<= 1) rs += __shfl_xor(rs, o, 64);
      l_r[i] = l_r[i] * corr + rs;
      m_r[i] = mnew;
      #pragma unroll
      for (int no = 0; no < 4; no++) oacc[no][i] *= corr;
      int row = wv*16 + quad*4 + i;
      #pragma unroll
      for (int ni = 0; ni < 4; ni++) Ps[row][ni*16 + r16] = f2h(ps[ni]);
    }
    __syncthreads();

    #pragma unroll
    for (int ks = 0; ks < 2; ks++){
      half8 paf = *(const half8*)&Ps[wv*16 + r16][ks*32 + quad*8];
      #pragma unroll
      for (int no = 0; no < 4; no++){
        half8 vbf = *(const half8*)&Vt[no*16 + r16][ks*32 + quad*8];
        oacc[no] = __builtin_amdgcn_mfma_f32_16x16x32_f16(paf, vbf, oacc[no], 0,0,0);
      }
    }
    __syncthreads();
  }

  #pragma unroll
  for (int i = 0; i < 4; i++){
    int qg = q0 + wv*16 + quad*4 + i;
    float inv = 1.f / l_r[i];
    #pragma unroll
    for (int no = 0; no < 4; no++){
      int dcol = no*16 + r16;
      attn[((long)(b*S_ + qg))*H_ + hh*64 + dcol] = f2h(oacc[no][i] * inv);
    }
  }
}

// ---------------- conversion: fp32 -> fp16, vectorized ----------------
__global__ void cvt_k(const float* __restrict__ src, half_t* __restrict__ dst, long n){
  long i = ((long)blockIdx.x*256 + threadIdx.x) * 8;
  long stride = (long)gridDim.x * 256 * 8;
  for (; i < n; i += stride){
    float4 a = *(const float4*)(src + i);
    float4 b = *(const float4*)(src + i + 4);
    HPk pk;
    pk.u[0]=f2h(a.x); pk.u[1]=f2h(a.y); pk.u[2]=f2h(a.z); pk.u[3]=f2h(a.w);
    pk.u[4]=f2h(b.x); pk.u[5]=f2h(b.y); pk.u[6]=f2h(b.z); pk.u[7]=f2h(b.w);
    *(half8*)(dst + i) = pk.v;
  }
}

__global__ void cvt_off_k(const float* __restrict__ src, half_t* __restrict__ dst,
                          long chunk, long dstStride, long dstOff, long total){
  long i = ((long)blockIdx.x*256 + threadIdx.x) * 8;
  long stride = (long)gridDim.x * 256 * 8;
  for (; i < total; i += stride){
    long l = i / chunk, r = i - l*chunk;
    float4 a = *(const float4*)(src + i);
    float4 b = *(const float4*)(src + i + 4);
    HPk pk;
    pk.u[0]=f2h(a.x); pk.u[1]=f2h(a.y); pk.u[2]=f2h(a.z); pk.u[3]=f2h(a.w);
    pk.u[4]=f2h(b.x); pk.u[5]=f2h(b.y); pk.u[6]=f2h(b.z); pk.u[7]=f2h(b.w);
    *(half8*)(dst + l*dstStride + dstOff + r) = pk.v;
  }
}

// ---------------- fused rms-normalize ----------------
__global__ void normh_k(const float* __restrict__ x, int ld, int n,
                        const float* __restrict__ w, half_t* __restrict__ out){
  int t = blockIdx.x;
  const float* p = x + (long)t*ld;
  float s = 0.f;
  for (int i = threadIdx.x; i < n; i += 256){ float v = p[i]; s += v*v; }
  s = blockReduceSum256(s);
  float rs = rsqrtf(s/(float)n + 1e-6f);
  half_t* o = out + (long)t*n;
  for (int i = threadIdx.x; i < n; i += 256) o[i] = f2h(p[i]*rs*w[i]);
}

// ---------------- fused rms-normalize + MoE gate top-2 ----------------
__global__ void normgate_k(const float* __restrict__ x,
                           const float* __restrict__ mnw,
                           const float* __restrict__ gw,
                           half_t* __restrict__ xm,
                           int* __restrict__ topi, float* __restrict__ topv){
  int t = blockIdx.x;
  int tid = threadIdx.x;
  int wv = tid >> 6, lane = tid & 63;
  const float* p = x + (long)t*H_;
  float s = 0.f;
  for (int i = tid; i < H_; i += 256){ float v = p[i]; s += v*v; }
  s = blockReduceSum256(s);
  float rs = rsqrtf(s/(float)H_ + 1e-6f);
  half_t* o = xm + (long)t*H_;
  float acc[E_];
  #pragma unroll
  for (int e = 0; e < E_; e++) acc[e] = 0.f;
  for (int i = tid; i < H_; i += 256){
    float xv = p[i]*rs*mnw[i];
    o[i] = f2h(xv);
    #pragma unroll
    for (int e = 0; e < E_; e++) acc[e] += xv * gw[e*H_ + i];
  }
  __shared__ float lsum[E_][4];
  #pragma unroll
  for (int e = 0; e < E_; e++){
    float v = acc[e];
    #pragma unroll
    for (int o2 = 32; o2 > 0; o2 >>= 1) v += __shfl_down(v, o2, 64);
    if (lane == 0) lsum[e][wv] = v;
  }
  __syncthreads();
  if (tid == 0){
    float logits[E_];
    #pragma unroll
    for (int e = 0; e < E_; e++) logits[e] = lsum[e][0]+lsum[e][1]+lsum[e][2]+lsum[e][3];
    int i0 = 0; float m0 = -1e30f;
    for (int e = 0; e < E_; e++) if (logits[e] > m0){ m0 = logits[e]; i0 = e; }
    int i1 = 0; float m1 = -1e30f;
    for (int e = 0; e < E_; e++) if (e != i0 && logits[e] > m1){ m1 = logits[e]; i1 = e; }
    float e1 = expf(m1 - m0); float z = 1.f + e1;
    topi[t*2] = i0; topi[t*2+1] = i1;
    topv[t*2] = 1.f/z; topv[t*2+1] = e1/z;
  }
}

// ---------------- small kernels ----------------
__global__ void rope_tab_k(float* cosb, float* sinb){ // grid S_, block 32
  int s = blockIdx.x, d = threadIdx.x;
  float inv = powf(10000.f, -(float)(2*d)/(2.f*DR_));
  float f = (float)s * inv;
  cosb[s*32+d] = cosf(f);
  sinb[s*32+d] = sinf(f);
}

__global__ void route_k(const int* __restrict__ topi, const float* __restrict__ topv,
                        int* __restrict__ poff, int* __restrict__ tok, float* __restrict__ rw){
  __shared__ int cnt[8], fill[8], off_s[9];
  int tid = threadIdx.x;
  if (tid < 8){ cnt[tid] = 0; fill[tid] = 0; }
  __syncthreads();
  atomicAdd(&cnt[topi[tid*2]], 1);
  atomicAdd(&cnt[topi[tid*2+1]], 1);
  __syncthreads();
  if (tid == 0){
    int o = 0;
    for (int e = 0; e < E_; e++){ off_s[e] = o; o += (cnt[e] + 63) & ~63; }
    off_s[E_] = o;
    for (int e = 0; e <= E_; e++) poff[e] = off_s[e];
  }
  __syncthreads();
  for (int i = tid; i < MOECAP; i += 1024){ tok[i] = -1; rw[i] = 0.f; }
  __syncthreads();
  #pragma unroll
  for (int j = 0; j < 2; j++){
    int e = topi[tid*2+j];
    int pos = atomicAdd(&fill[e], 1);
    int idx = off_s[e] + pos;
    tok[idx] = tid; rw[idx] = topv[tid*2+j];
  }
}

__global__ void head_k(const float* __restrict__ h, const float* __restrict__ fnw,
                       const float* __restrict__ hw, const float* __restrict__ hb,
                       float* __restrict__ out){
  int b = blockIdx.x; int t = b*S_ + S_ - 1;
  const float* hp = h + (long)t*H_;
  float ss = 0.f;
  for (int j = threadIdx.x; j < H_; j += 256){ float v = hp[j]; ss += v*v; }
  ss = blockReduceSum256(ss);
  __shared__ float rs_s;
  if (threadIdx.x == 0) rs_s = rsqrtf(ss/(float)H_ + 1e-6f);
  __syncthreads();
  float rs = rs_s;
  float d = 0.f;
  for (int j = threadIdx.x; j < H_; j += 256) d += hp[j]*rs*fnw[j]*hw[j];
  d = blockReduceSum256(d);
  if (threadIdx.x == 0) out[b] = d + hb[0];
}

// ---------------- host ----------------
extern "C" void kernel_launch(void* const* d_in, const int* in_sizes, int n_in,
                              void* d_out, int out_size, void* d_ws, size_t ws_size,
                              hipStream_t stream) {
  const float* inputs = (const float*)d_in[0];
  const float* in_w   = (const float*)d_in[1];
  const float* in_b   = (const float*)d_in[2];
  const float* anw_a  = (const float*)d_in[3];
  const float* wq_a   = (const float*)d_in[4];
  const float* wkva_a = (const float*)d_in[5];
  const float* kvn_a  = (const float*)d_in[6];
  const float* wkvb_a = (const float*)d_in[7];
  const float* wo_a   = (const float*)d_in[8];
  const float* mnw_a  = (const float*)d_in[9];
  const float* gw_a   = (const float*)d_in[10];
  const float* w1_a   = (const float*)d_in[11];
  const float* w2_a   = (const float*)d_in[12];
  const float* w3_a   = (const float*)d_in[13];
  const float* sw1_a  = (const float*)d_in[14];
  const float* sw2_a  = (const float*)d_in[15];
  const float* sw3_a  = (const float*)d_in[16];
  const float* fnw    = (const float*)d_in[17];
  const float* hw     = (const float*)d_in[18];
  const float* hb     = (const float*)d_in[19];
  (void)in_sizes; (void)n_in; (void)out_size;

  char* p = (char*)d_ws;
  auto alloc = [&](size_t bytes)->char*{
    char* r = p; p += (bytes + 255) & ~(size_t)255; return r;
  };
  // ---- activations ----
  float*  h_      = (float*) alloc((size_t)T_*H_*4);
  float*  ckv_    = (float*) alloc((size_t)T_*512*4);
  half_t* kvb_    = (half_t*)alloc((size_t)T_*1152*2);
  half_t* Qp_     = (half_t*)alloc((size_t)B_*NH_*S_*64*2);
  half_t* Kpe_    = (half_t*)alloc((size_t)T_*32*2);
  half_t* attn_   = (half_t*)alloc((size_t)T_*H_*2);
  half_t* g_      = (half_t*)alloc((size_t)MOECAP*I_*2);
  half_t* gs_     = (half_t*)alloc((size_t)T_*SI_*2);
  half_t* xh_     = (half_t*)alloc((size_t)T_*H_*2);     // rms(h)*anw  fp16
  half_t* xm_     = (half_t*)alloc((size_t)T_*H_*2);     // rms(h)*mnw  fp16
  half_t* ckvh_   = (half_t*)alloc((size_t)T_*R_*2);     // rms(c_kv)*kvn fp16
  half_t* inh_    = (half_t*)alloc((size_t)T_*64*2);     // inputs fp16
  half_t* inwh_   = (half_t*)alloc((size_t)768*64*2);    // in_w fp16
  float*  cosb_   = (float*) alloc((size_t)S_*32*4);
  float*  sinb_   = (float*) alloc((size_t)S_*32*4);
  float*  topv_   = (float*) alloc((size_t)T_*2*4);
  int*    topi_   = (int*)   alloc((size_t)T_*2*4);
  int*    poff_   = (int*)   alloc(64);
  int*    tok_    = (int*)   alloc((size_t)MOECAP*4);
  float*  rw_     = (float*) alloc((size_t)MOECAP*4);

  // ---- fp16 weight image ----
  const size_t nWQ1   = (size_t)768*H_;
  const size_t nWKVA1 = (size_t)544*H_;
  const size_t nQKV1  = (size_t)NQKV*H_;
  const size_t nWKVB1 = (size_t)1152*R_;
  const size_t nWO1   = (size_t)H_*768;
  const size_t nE1    = (size_t)E_*I_*H_;
  const size_t nSW1   = (size_t)SI_*H_;
  const size_t perLayer = nQKV1+nWKVB1+nWO1+3*nE1+3*nSW1;
  const size_t allw = (size_t)L_ * perLayer * 2;
  size_t usedAct = (size_t)(p - (char*)d_ws);
  bool big = (ws_size == 0) || (usedAct + allw + (size_t)(1u<<20) <= ws_size);

  half_t *qkvW,*wkvbW,*woW,*e1W,*e2W,*e3W,*sw1W,*sw2W,*sw3W;
  if (big){
    qkvW  = (half_t*)alloc((size_t)L_*nQKV1*2);
    wkvbW = (half_t*)alloc((size_t)L_*nWKVB1*2);
    woW   = (half_t*)alloc((size_t)L_*nWO1*2);
    e1W   = (half_t*)alloc((size_t)L_*nE1*2);
    e2W   = (half_t*)alloc((size_t)L_*nE1*2);
    e3W   = (half_t*)alloc((size_t)L_*nE1*2);
    sw1W  = (half_t*)alloc((size_t)L_*nSW1*2);
    sw2W  = (half_t*)alloc((size_t)L_*nSW1*2);
    sw3W  = (half_t*)alloc((size_t)L_*nSW1*2);
  } else {
    qkvW  = (half_t*)alloc(nQKV1*2);
    wkvbW = (half_t*)alloc(nWKVB1*2);
    woW   = (half_t*)alloc(nWO1*2);
    e1W   = (half_t*)alloc(nE1*2);
    e2W   = (half_t*)alloc(nE1*2);
    e3W   = (half_t*)alloc(nE1*2);
    sw1W  = (half_t*)alloc(nSW1*2);
    sw2W  = (half_t*)alloc(nSW1*2);
    sw3W  = (half_t*)alloc(nSW1*2);
  }

  auto cvt = [&](const float* s, half_t* d, size_t n){
    long blocks = (long)((n/8 + 255) / 256);
    int grid = (int)(blocks > 2048 ? 2048 : blocks);
    cvt_k<<<grid, 256, 0, stream>>>(s, d, (long)n);
  };
  auto cvt_off = [&](const float* s, half_t* d, size_t chunk, size_t dstStride,
                     size_t dstOff, size_t total){
    long blocks = (long)((total/8 + 255) / 256);
    int grid = (int)(blocks > 2048 ? 2048 : blocks);
    cvt_off_k<<<grid, 256, 0, stream>>>(s, d, (long)chunk, (long)dstStride,
                                        (long)dstOff, (long)total);
  };

  cvt(inputs, inh_, (size_t)T_*64);
  cvt(in_w,   inwh_,(size_t)768*64);
  if (big){
    cvt_off(wq_a,   qkvW, nWQ1,   nQKV1, 0,     (size_t)L_*nWQ1);
    cvt_off(wkva_a, qkvW, nWKVA1, nQKV1, nWQ1,  (size_t)L_*nWKVA1);
    cvt(wkvb_a, wkvbW, (size_t)L_*nWKVB1);
    cvt(wo_a,   woW,   (size_t)L_*nWO1);
    cvt(w1_a,   e1W,   (size_t)L_*nE1);
    cvt(w2_a,   e2W,   (size_t)L_*nE1);
    cvt(w3_a,   e3W,   (size_t)L_*nE1);
    cvt(sw1_a,  sw1W,  (size_t)L_*nSW1);
    cvt(sw2_a,  sw2W,  (size_t)L_*nSW1);
    cvt(sw3_a,  sw3W,  (size_t)L_*nSW1);
  }

  rope_tab_k<<<S_, 32, 0, stream>>>(cosb_, sinb_);

  auto mk = [&](const half_t* A, int lda, const half_t* W, int ldw,
                const half_t* W3, void* C, int ldc, int M, int N, int Kd)->GArgs{
    GArgs ga;
    ga.Ab=A; ga.lda=lda; ga.Wb=W; ga.ldw=ldw; ga.W3b=W3;
    ga.Cg=C; ga.ldc=ldc; ga.M=M; ga.N=N; ga.Kd=Kd;
    ga.bias=nullptr; ga.hres=nullptr; ga.tok=nullptr; ga.rw=nullptr; ga.poff=nullptr;
    ga.cosb=nullptr; ga.sinb=nullptr; ga.kpe=nullptr; ga.ckv=nullptr;
    return ga;
  };

  {
    GArgs ga = mk(inh_,64, inwh_,64, nullptr, h_,768, T_,768,64);
    ga.bias = in_b;
    gemm_k<GM_F32OUT><<<dim3(16,12), 256, SM_NF, stream>>>(ga);
  }

  for (int l = 0; l < L_; l++) {
    const float* anw  = anw_a  + (size_t)l*H_;
    const float* kvn  = kvn_a  + (size_t)l*R_;
    const float* mnw  = mnw_a  + (size_t)l*H_;
    const float* gw_l = gw_a   + (size_t)l*E_*H_;

    const half_t* qkvh  = big ? qkvW  + (size_t)l*nQKV1  : qkvW;
    const half_t* wkvbh = big ? wkvbW + (size_t)l*nWKVB1 : wkvbW;
    const half_t* woh   = big ? woW   + (size_t)l*nWO1   : woW;
    const half_t* e1h   = big ? e1W   + (size_t)l*nE1    : e1W;
    const half_t* e2h   = big ? e2W   + (size_t)l*nE1    : e2W;
    const half_t* e3h   = big ? e3W   + (size_t)l*nE1    : e3W;
    const half_t* sw1h  = big ? sw1W  + (size_t)l*nSW1   : sw1W;
    const half_t* sw2h  = big ? sw2W  + (size_t)l*nSW1   : sw2W;
    const half_t* sw3h  = big ? sw3W  + (size_t)l*nSW1   : sw3W;

    if (!big){
      cvt(wq_a   + (size_t)l*nWQ1,   qkvW,         nWQ1);
      cvt(wkva_a + (size_t)l*nWKVA1, qkvW + nWQ1,  nWKVA1);
      cvt(wkvb_a + (size_t)l*nWKVB1, wkvbW, nWKVB1);
      cvt(wo_a   + (size_t)l*nWO1,   woW,   nWO1);
      cvt(w1_a   + (size_t)l*nE1,    e1W,   nE1);
      cvt(w2_a   + (size_t)l*nE1,    e2W,   nE1);
      cvt(w3_a   + (size_t)l*nE1,    e3W,   nE1);
      cvt(sw1_a  + (size_t)l*nSW1,   sw1W,  nSW1);
      cvt(sw2_a  + (size_t)l*nSW1,   sw2W,  nSW1);
      cvt(sw3_a  + (size_t)l*nSW1,   sw3W,  nSW1);
    }

    // ---- attention ----
    normh_k<<<T_, 256, 0, stream>>>(h_, H_, H_, anw, xh_);
    {
      GArgs ga = mk(xh_,H_, qkvh,H_, nullptr, Qp_,0, T_,NQKV,H_);
      ga.cosb = cosb_; ga.sinb = sinb_; ga.kpe = Kpe_; ga.ckv = ckv_;
      gemm_k<GM_QKV><<<dim3(16,21), 256, SM_NF, stream>>>(ga);
    }
    normh_k<<<T_, 256, 0, stream>>>(ckv_, 512, R_, kvn, ckvh_);
    {
      GArgs ga = mk(ckvh_,R_, wkvbh,R_, nullptr, kvb_,1152, T_,1152,R_);
      gemm_k<GM_H16OUT><<<dim3(16,18), 256, SM_NF, stream>>>(ga);
    }
    fattn_k<<<dim3(S_/64, B_*NH_), 256, 0, stream>>>(Qp_, Kpe_, kvb_, attn_);
    {
      GArgs ga = mk(attn_,H_, woh,768, nullptr, nullptr,H_, T_,H_,768);
      ga.hres = h_;
      gemm_k<GM_RESADD><<<dim3(16,12), 256, SM_NF, stream>>>(ga);
    }

    // ---- MoE + shared expert ----
    normgate_k<<<T_, 256, 0, stream>>>(h_, mnw, gw_l, xm_, topi_, topv_);
    route_k<<<1, 1024, 0, stream>>>(topi_, topv_, poff_, tok_, rw_);
    {
      GArgs gsA = mk(xm_,H_, sw1h,H_, sw3h, gs_,SI_, T_,SI_,H_);
      GArgs gmB = mk(xm_,H_, e1h,H_, e3h, g_,I_, MOECAP,I_,H_);
      gmB.tok = tok_; gmB.rw = rw_; gmB.poff = poff_;
      gemm2_k<GM_SILU, GM_MOE13><<<dim3(MOECAP/64, 20), 256, SM_F, stream>>>(gsA, gmB, 16);
    }
    {
      GArgs gmA = mk(g_,I_, e2h,I_, nullptr, nullptr,H_, MOECAP,H_,I_);
      gmA.hres = h_; gmA.tok = tok_; gmA.rw = rw_; gmA.poff = poff_;
      GArgs gsB = mk(gs_,SI_, sw2h,SI_, nullptr, nullptr,H_, T_,H_,SI_);
      gsB.hres = h_;
      gemm2_k<GM_MOE2, GM_RESADDA><<<dim3(MOECAP/64, 24), 256, SM_NF, stream>>>(gmA, gsB, 12);
    }
  }

  head_k<<<B_, 256, 0, stream>>>(h_, fnw, hw, hb, (float*)d_out);
}